// Round 18
// baseline (93.447 us; speedup 1.0000x reference)
//
#include <hip/hip_runtime.h>
#include <hip/hip_bf16.h>

#define B_  512
#define T_  256
#define C_  384
#define H_  64
#define SCALE_ 0.05103103630798287f   // 384^-0.5

typedef float f32x4  __attribute__((ext_vector_type(4)));
typedef short bf16x8 __attribute__((ext_vector_type(8)));
typedef short bf16x4 __attribute__((ext_vector_type(4)));

__device__ __forceinline__ unsigned short f2bf(float f) {
    union { float f; unsigned u; } v; v.f = f;
    unsigned r = v.u + 0x7FFFu + ((v.u >> 16) & 1u);   // RNE
    return (unsigned short)(r >> 16);
}
__device__ __forceinline__ unsigned cvt_pk_bf16(float lo, float hi) {
    unsigned r;
    asm("v_cvt_pk_bf16_f32 %0, %1, %2" : "=v"(r) : "v"(lo), "v"(hi));
    return r;
}
// XOR-swizzled [R][64]-short tile index (row = 128 B = 8 x 16B blocks).
__device__ __forceinline__ int swz64(int row, int col) {
    return row * 64 + (((col >> 3) ^ (row & 7)) << 3) + (col & 7);
}

// ---------------- Prep: Wv (f32 [384][64]) -> Wtv bf16 [64][384] in d_ws ----------
__global__ void transpose_wv_kernel(const float* __restrict__ Wv, short* __restrict__ Wtv) {
    const int idx = blockIdx.x * 256 + threadIdx.x;   // 0..3071
    const int n  = idx / 48;
    const int kb = (idx % 48) * 8;
    short* dst = Wtv + n * 384;
    #pragma unroll
    for (int k = kb; k < kb + 8; k++) dst[k] = (short)f2bf(Wv[(size_t)k * H_ + n]);
}

// =====================================================================
// WS variant: K/Q columns (nb 0..7) from resident LDS; V columns (nb 8..11)
// streamed from global bf16 Wtv (L2-resident) — two pipes in parallel.
// LDS (shorts): smem[53760] = 107520 B.
//  Phase-1: Wl[j] at j*8192, j=0..5 — six k=64 chunks of [128 rows (K,Q)][64].
//  Phase-2 (alias): Ks[0,16384) swz64 | Vt[16384,33280) | Pb[33280,53760)
// =====================================================================
__global__ __launch_bounds__(1024, 4) void att_head_ws(
    const float* __restrict__ x,  const float* __restrict__ Wk,
    const float* __restrict__ Wq, const short* __restrict__ Wtv,
    float* __restrict__ out)
{
    __shared__ __align__(16) short smem[53760];
    short* const Ks = smem;              // alias (live after phase 1)
    short* const Vt = smem + 16384;
    short* const Pb = smem + 33280;

    const int tid  = threadIdx.x;
    const int b    = blockIdx.x;
    const int w    = tid >> 6;
    const int lane = tid & 63;
    const int g    = lane >> 4;
    const int i    = lane & 15;
    const int rb   = 16 * w;

    const float* xb = x + (size_t)b * T_ * C_;
    const float* Wm[2] = { Wk, Wq };

    f32x4 accP[12];
    #pragma unroll
    for (int nb = 0; nb < 12; nb++) accP[nb] = f32x4{0.f, 0.f, 0.f, 0.f};

    const float* xrow = xb + (size_t)(rb + i) * C_ + g * 8;

    // ---- Stage ALL 6 chunks of K,Q columns (R17 pattern, m=0..1 only) ----
    {
        float wfa[8], wfb[8];
        auto loadWchunk = [&](int j, float* dst) {
            #pragma unroll
            for (int m = 0; m < 2; m++) {
                const float* Wp = Wm[m] + (size_t)(j * 64 + w * 4) * H_ + lane;
                #pragma unroll
                for (int jj = 0; jj < 4; jj++) dst[m * 4 + jj] = Wp[jj * H_];
            }
        };
        auto writeWchunk = [&](int j, const float* src) {
            short* buf = smem + j * 8192;
            #pragma unroll
            for (int m = 0; m < 2; m++) {
                union { unsigned u; short s[2]; } p0, p1;
                p0.u = cvt_pk_bf16(src[4 * m + 0], src[4 * m + 1]);
                p1.u = cvt_pk_bf16(src[4 * m + 2], src[4 * m + 3]);
                bf16x4 pk;
                pk[0] = p0.s[0]; pk[1] = p0.s[1]; pk[2] = p1.s[0]; pk[3] = p1.s[1];
                const int row = m * 64 + lane;
                const int k0  = w * 4;
                *(bf16x4*)&buf[row * 64 + (((k0 >> 3) ^ (row & 7)) << 3) + (k0 & 7)] = pk;
            }
        };
        loadWchunk(0, wfa);
        #pragma unroll
        for (int j = 0; j < 6; j++) {
            float* curW = (j & 1) ? wfb : wfa;
            float* nxtW = (j & 1) ? wfa : wfb;
            if (j < 5) loadWchunk(j + 1, nxtW);
            writeWchunk(j, curW);
        }
    }
    float4 xr[2][4];
    #pragma unroll
    for (int ks = 0; ks < 2; ks++)
        #pragma unroll
        for (int h = 0; h < 2; h++)
            xr[0][ks * 2 + h] = *(const float4*)(xrow + ks * 32 + h * 4);
    asm volatile("s_waitcnt lgkmcnt(0)\n\ts_barrier" ::: "memory");

    // ---- Phase 1: barrier-free; nb0..7 via LDS, nb8..11 via global Wtv ----
    const short* wtv0 = Wtv + (size_t)i * 384 + 8 * g;
    #pragma unroll
    for (int j = 0; j < 6; j++) {
        const int par = j & 1;
        const short* cur = smem + j * 8192;
        if (j < 5) {
            #pragma unroll
            for (int ks = 0; ks < 2; ks++)
                #pragma unroll
                for (int h = 0; h < 2; h++)
                    xr[par ^ 1][ks * 2 + h] = *(const float4*)(xrow + (j + 1) * 64 + ks * 32 + h * 4);
        }
        bf16x8 afs[2];
        #pragma unroll
        for (int ks = 0; ks < 2; ks++)
            #pragma unroll
            for (int h = 0; h < 2; h++) {
                const float4 v = xr[par][ks * 2 + h];
                afs[ks][h * 4 + 0] = (short)f2bf(v.x);
                afs[ks][h * 4 + 1] = (short)f2bf(v.y);
                afs[ks][h * 4 + 2] = (short)f2bf(v.z);
                afs[ks][h * 4 + 3] = (short)f2bf(v.w);
            }
        #pragma unroll
        for (int ks = 0; ks < 2; ks++) {
            bf16x8 vf[4];
            #pragma unroll
            for (int nbv = 0; nbv < 4; nbv++)
                vf[nbv] = *(const bf16x8*)(wtv0 + (size_t)(16 * nbv) * 384 + 64 * j + 32 * ks);
            #pragma unroll
            for (int nb = 0; nb < 8; nb++) {
                const int brow = nb * 16 + i;
                const bf16x8 bfr = *(const bf16x8*)&cur[brow * 64 + (((ks * 4 + g) ^ (i & 7)) << 3)];
                accP[nb] = __builtin_amdgcn_mfma_f32_16x16x32_bf16(afs[ks], bfr, accP[nb], 0, 0, 0);
            }
            #pragma unroll
            for (int nbv = 0; nbv < 4; nbv++)
                accP[8 + nbv] = __builtin_amdgcn_mfma_f32_16x16x32_bf16(afs[ks], vf[nbv], accP[8 + nbv], 0, 0, 0);
        }
    }
    asm volatile("s_waitcnt lgkmcnt(0)\n\ts_barrier" ::: "memory");

    // ---- Epilogue (R9/R17 verbatim) ----
    #pragma unroll
    for (int nb = 0; nb < 4; nb++)
        #pragma unroll
        for (int r = 0; r < 4; r++)
            Ks[swz64(rb + 4 * g + r, 16 * nb + i)] = (short)f2bf(accP[4 + nb][r]);
    asm volatile("s_waitcnt lgkmcnt(0)" ::: "memory");
    bf16x8 qf[2];
    #pragma unroll
    for (int ks = 0; ks < 2; ks++)
        qf[ks] = *(const bf16x8*)&Ks[(rb + i) * 64 + (((4 * ks + g) ^ (i & 7)) << 3)];
    asm volatile("s_waitcnt lgkmcnt(0)" ::: "memory");
    #pragma unroll
    for (int nb = 0; nb < 4; nb++)
        #pragma unroll
        for (int r = 0; r < 4; r++)
            Ks[swz64(rb + 4 * g + r, 16 * nb + i)] = (short)f2bf(accP[nb][r]);
    #pragma unroll
    for (int nb = 0; nb < 4; nb++) {
        bf16x4 pk;
        #pragma unroll
        for (int r = 0; r < 4; r++) pk[r] = (short)f2bf(accP[8 + nb][r]);
        *(bf16x4*)&Vt[(16 * nb + i) * 264 + rb + 4 * g] = pk;
    }
    asm volatile("s_waitcnt lgkmcnt(0)\n\ts_barrier" ::: "memory");

    // ---- Phase 2 (R9/R17 verbatim): online causal attention, S^T ----
    short* const myP = Pb + w * 1280;
    const float NEG_INF = -__builtin_inff();
    float mrun = NEG_INF, lrun = 0.f;
    f32x4 accO[4];
    #pragma unroll
    for (int ht = 0; ht < 4; ht++) accO[ht] = f32x4{0.f, 0.f, 0.f, 0.f};

    auto PVADD = [&](int bufsel, int ck) {
        const bf16x8 pf = *(const bf16x8*)&myP[bufsel * 640 + i * 40 + 8 * g];
        #pragma unroll
        for (int ht = 0; ht < 4; ht++) {
            const bf16x8 vfx = *(const bf16x8*)&Vt[(16 * ht + i) * 264 + 32 * ck + 8 * g];
            accO[ht] = __builtin_amdgcn_mfma_f32_16x16x32_bf16(vfx, pf, accO[ht], 0, 0, 0);
        }
    };

    const int npair = w >> 1;
    #pragma unroll
    for (int p = 0; p < 8; p++) {
        if (p <= npair) {
            f32x4 sA[2];
            sA[0] = f32x4{0.f, 0.f, 0.f, 0.f};
            sA[1] = f32x4{0.f, 0.f, 0.f, 0.f};
            #pragma unroll
            for (int s = 0; s < 2; s++) {
                const int nt = 2 * p + s;
                if (nt <= w) {
                    #pragma unroll
                    for (int ks = 0; ks < 2; ks++) {
                        const bf16x8 kfr = *(const bf16x8*)&Ks[(16 * nt + i) * 64 +
                                (((4 * ks + g) ^ (i & 7)) << 3)];
                        sA[s] = __builtin_amdgcn_mfma_f32_16x16x32_bf16(kfr, qf[ks], sA[s], 0, 0, 0);
                    }
                }
            }
            if (p > 0) PVADD((p - 1) & 1, p - 1);

            float mt = NEG_INF;
            #pragma unroll
            for (int s = 0; s < 2; s++)
                #pragma unroll
                for (int r = 0; r < 4; r++) {
                    const int kv = 16 * (2 * p + s) + 4 * g + r;
                    const bool ok = (2 * p + s <= w) && (kv <= rb + i);
                    const float v = ok ? sA[s][r] * SCALE_ : NEG_INF;
                    sA[s][r] = v;
                    mt = fmaxf(mt, v);
                }
            mt = fmaxf(mt, __shfl_xor(mt, 16, 64));
            mt = fmaxf(mt, __shfl_xor(mt, 32, 64));

            if (!__all(mt <= mrun + 8.0f)) {
                const float mnew = fmaxf(mrun, mt);
                const float f = __expf(mrun - mnew);
                mrun = mnew; lrun *= f;
                #pragma unroll
                for (int ht = 0; ht < 4; ht++)
                    #pragma unroll
                    for (int r = 0; r < 4; r++) accO[ht][r] *= f;
            }
            #pragma unroll
            for (int s = 0; s < 2; s++) {
                const float p0 = __expf(sA[s][0] - mrun);
                const float p1 = __expf(sA[s][1] - mrun);
                const float p2 = __expf(sA[s][2] - mrun);
                const float p3 = __expf(sA[s][3] - mrun);
                lrun += (p0 + p1) + (p2 + p3);
                union { bf16x4 v; unsigned u[2]; } pk;
                pk.u[0] = cvt_pk_bf16(p0, p1);
                pk.u[1] = cvt_pk_bf16(p2, p3);
                *(bf16x4*)&myP[(p & 1) * 640 + i * 40 + 16 * s + 4 * g] = pk.v;
            }
        }
    }
    PVADD(npair & 1, npair);

    lrun += __shfl_xor(lrun, 16, 64);
    lrun += __shfl_xor(lrun, 32, 64);
    const float inv = 1.f / lrun;

    float* orow = out + ((size_t)b * T_ + rb + i) * H_;
    #pragma unroll
    for (int ht = 0; ht < 4; ht++) {
        float4 o;
        o.x = accO[ht][0] * inv;
        o.y = accO[ht][1] * inv;
        o.z = accO[ht][2] * inv;
        o.w = accO[ht][3] * inv;
        *(float4*)&orow[16 * ht + 4 * g] = o;
    }
}

// =====================================================================
// Fallback: R17 kernel verbatim (56.9 us) — used when ws_size < 49152.
// =====================================================================
__global__ __launch_bounds__(1024, 4) void att_head_kernel(
    const float* __restrict__ x,  const float* __restrict__ Wk,
    const float* __restrict__ Wq, const float* __restrict__ Wv,
    float* __restrict__ out)
{
    __shared__ __align__(16) short smem[73728];
    short* const Ks = smem;
    short* const Vt = smem + 16384;
    short* const Pb = smem + 33280;

    const int tid  = threadIdx.x;
    const int b    = blockIdx.x;
    const int w    = tid >> 6;
    const int lane = tid & 63;
    const int g    = lane >> 4;
    const int i    = lane & 15;
    const int rb   = 16 * w;

    const float* xb = x + (size_t)b * T_ * C_;
    const float* Wm[3] = { Wk, Wq, Wv };

    f32x4 accP[12];
    #pragma unroll
    for (int nb = 0; nb < 12; nb++) accP[nb] = f32x4{0.f, 0.f, 0.f, 0.f};

    const float* xrow = xb + (size_t)(rb + i) * C_ + g * 8;

    {
        float wfa[12], wfb[12];
        auto loadWchunk = [&](int j, float* dst) {
            #pragma unroll
            for (int m = 0; m < 3; m++) {
                const float* Wp = Wm[m] + (size_t)(j * 64 + w * 4) * H_ + lane;
                #pragma unroll
                for (int jj = 0; jj < 4; jj++) dst[m * 4 + jj] = Wp[jj * H_];
            }
        };
        auto writeWchunk = [&](int j, const float* src) {
            short* buf = smem + j * 12288;
            #pragma unroll
            for (int m = 0; m < 3; m++) {
                union { unsigned u; short s[2]; } p0, p1;
                p0.u = cvt_pk_bf16(src[4 * m + 0], src[4 * m + 1]);
                p1.u = cvt_pk_bf16(src[4 * m + 2], src[4 * m + 3]);
                bf16x4 pk;
                pk[0] = p0.s[0]; pk[1] = p0.s[1]; pk[2] = p1.s[0]; pk[3] = p1.s[1];
                const int row = m * 64 + lane;
                const int k0  = w * 4;
                *(bf16x4*)&buf[row * 64 + (((k0 >> 3) ^ (row & 7)) << 3) + (k0 & 7)] = pk;
            }
        };
        loadWchunk(0, wfa);
        #pragma unroll
        for (int j = 0; j < 6; j++) {
            float* curW = (j & 1) ? wfb : wfa;
            float* nxtW = (j & 1) ? wfa : wfb;
            if (j < 5) loadWchunk(j + 1, nxtW);
            writeWchunk(j, curW);
        }
    }
    float4 xr[2][4];
    #pragma unroll
    for (int ks = 0; ks < 2; ks++)
        #pragma unroll
        for (int h = 0; h < 2; h++)
            xr[0][ks * 2 + h] = *(const float4*)(xrow + ks * 32 + h * 4);
    asm volatile("s_waitcnt lgkmcnt(0)\n\ts_barrier" ::: "memory");

    #pragma unroll
    for (int j = 0; j < 6; j++) {
        const int par = j & 1;
        const short* cur = smem + j * 12288;
        if (j < 5) {
            #pragma unroll
            for (int ks = 0; ks < 2; ks++)
                #pragma unroll
                for (int h = 0; h < 2; h++)
                    xr[par ^ 1][ks * 2 + h] = *(const float4*)(xrow + (j + 1) * 64 + ks * 32 + h * 4);
        }
        bf16x8 afs[2];
        #pragma unroll
        for (int ks = 0; ks < 2; ks++)
            #pragma unroll
            for (int h = 0; h < 2; h++) {
                const float4 v = xr[par][ks * 2 + h];
                afs[ks][h * 4 + 0] = (short)f2bf(v.x);
                afs[ks][h * 4 + 1] = (short)f2bf(v.y);
                afs[ks][h * 4 + 2] = (short)f2bf(v.z);
                afs[ks][h * 4 + 3] = (short)f2bf(v.w);
            }
        #pragma unroll
        for (int nb = 0; nb < 12; nb++) {
            #pragma unroll
            for (int ks = 0; ks < 2; ks++) {
                const int brow = nb * 16 + i;
                const bf16x8 bfr = *(const bf16x8*)&cur[brow * 64 + (((ks * 4 + g) ^ (i & 7)) << 3)];
                accP[nb] = __builtin_amdgcn_mfma_f32_16x16x32_bf16(afs[ks], bfr, accP[nb], 0, 0, 0);
            }
        }
    }
    asm volatile("s_waitcnt lgkmcnt(0)\n\ts_barrier" ::: "memory");

    #pragma unroll
    for (int nb = 0; nb < 4; nb++)
        #pragma unroll
        for (int r = 0; r < 4; r++)
            Ks[swz64(rb + 4 * g + r, 16 * nb + i)] = (short)f2bf(accP[4 + nb][r]);
    asm volatile("s_waitcnt lgkmcnt(0)" ::: "memory");
    bf16x8 qf[2];
    #pragma unroll
    for (int ks = 0; ks < 2; ks++)
        qf[ks] = *(const bf16x8*)&Ks[(rb + i) * 64 + (((4 * ks + g) ^ (i & 7)) << 3)];
    asm volatile("s_waitcnt lgkmcnt(0)" ::: "memory");
    #pragma unroll
    for (int nb = 0; nb < 4; nb++)
        #pragma unroll
        for (int r = 0; r < 4; r++)
            Ks[swz64(rb + 4 * g + r, 16 * nb + i)] = (short)f2bf(accP[nb][r]);
    #pragma unroll
    for (int nb = 0; nb < 4; nb++) {
        bf16x4 pk;
        #pragma unroll
        for (int r = 0; r < 4; r++) pk[r] = (short)f2bf(accP[8 + nb][r]);
        *(bf16x4*)&Vt[(16 * nb + i) * 264 + rb + 4 * g] = pk;
    }
    asm volatile("s_waitcnt lgkmcnt(0)\n\ts_barrier" ::: "memory");

    short* const myP = Pb + w * 1280;
    const float NEG_INF = -__builtin_inff();
    float mrun = NEG_INF, lrun = 0.f;
    f32x4 accO[4];
    #pragma unroll
    for (int ht = 0; ht < 4; ht++) accO[ht] = f32x4{0.f, 0.f, 0.f, 0.f};

    auto PVADD = [&](int bufsel, int ck) {
        const bf16x8 pf = *(const bf16x8*)&myP[bufsel * 640 + i * 40 + 8 * g];
        #pragma unroll
        for (int ht = 0; ht < 4; ht++) {
            const bf16x8 vfx = *(const bf16x8*)&Vt[(16 * ht + i) * 264 + 32 * ck + 8 * g];
            accO[ht] = __builtin_amdgcn_mfma_f32_16x16x32_bf16(vfx, pf, accO[ht], 0, 0, 0);
        }
    };

    const int npair = w >> 1;
    #pragma unroll
    for (int p = 0; p < 8; p++) {
        if (p <= npair) {
            f32x4 sA[2];
            sA[0] = f32x4{0.f, 0.f, 0.f, 0.f};
            sA[1] = f32x4{0.f, 0.f, 0.f, 0.f};
            #pragma unroll
            for (int s = 0; s < 2; s++) {
                const int nt = 2 * p + s;
                if (nt <= w) {
                    #pragma unroll
                    for (int ks = 0; ks < 2; ks++) {
                        const bf16x8 kfr = *(const bf16x8*)&Ks[(16 * nt + i) * 64 +
                                (((4 * ks + g) ^ (i & 7)) << 3)];
                        sA[s] = __builtin_amdgcn_mfma_f32_16x16x32_bf16(kfr, qf[ks], sA[s], 0, 0, 0);
                    }
                }
            }
            if (p > 0) PVADD((p - 1) & 1, p - 1);

            float mt = NEG_INF;
            #pragma unroll
            for (int s = 0; s < 2; s++)
                #pragma unroll
                for (int r = 0; r < 4; r++) {
                    const int kv = 16 * (2 * p + s) + 4 * g + r;
                    const bool ok = (2 * p + s <= w) && (kv <= rb + i);
                    const float v = ok ? sA[s][r] * SCALE_ : NEG_INF;
                    sA[s][r] = v;
                    mt = fmaxf(mt, v);
                }
            mt = fmaxf(mt, __shfl_xor(mt, 16, 64));
            mt = fmaxf(mt, __shfl_xor(mt, 32, 64));

            if (!__all(mt <= mrun + 8.0f)) {
                const float mnew = fmaxf(mrun, mt);
                const float f = __expf(mrun - mnew);
                mrun = mnew; lrun *= f;
                #pragma unroll
                for (int ht = 0; ht < 4; ht++)
                    #pragma unroll
                    for (int r = 0; r < 4; r++) accO[ht][r] *= f;
            }
            #pragma unroll
            for (int s = 0; s < 2; s++) {
                const float p0 = __expf(sA[s][0] - mrun);
                const float p1 = __expf(sA[s][1] - mrun);
                const float p2 = __expf(sA[s][2] - mrun);
                const float p3 = __expf(sA[s][3] - mrun);
                lrun += (p0 + p1) + (p2 + p3);
                union { bf16x4 v; unsigned u[2]; } pk;
                pk.u[0] = cvt_pk_bf16(p0, p1);
                pk.u[1] = cvt_pk_bf16(p2, p3);
                *(bf16x4*)&myP[(p & 1) * 640 + i * 40 + 16 * s + 4 * g] = pk.v;
            }
        }
    }
    PVADD(npair & 1, npair);

    lrun += __shfl_xor(lrun, 16, 64);
    lrun += __shfl_xor(lrun, 32, 64);
    const float inv = 1.f / lrun;

    float* orow = out + ((size_t)b * T_ + rb + i) * H_;
    #pragma unroll
    for (int ht = 0; ht < 4; ht++) {
        float4 o;
        o.x = accO[ht][0] * inv;
        o.y = accO[ht][1] * inv;
        o.z = accO[ht][2] * inv;
        o.w = accO[ht][3] * inv;
        *(float4*)&orow[16 * ht + 4 * g] = o;
    }
}

extern "C" void kernel_launch(void* const* d_in, const int* in_sizes, int n_in,
                              void* d_out, int out_size, void* d_ws, size_t ws_size,
                              hipStream_t stream) {
    const float* x  = (const float*)d_in[0];
    const float* Wk = (const float*)d_in[1];
    const float* Wq = (const float*)d_in[2];
    const float* Wv = (const float*)d_in[3];
    float* out = (float*)d_out;
    (void)in_sizes; (void)n_in; (void)out_size;
    if (ws_size >= (size_t)(H_ * C_ * 2) && d_ws != nullptr) {
        short* Wtv = (short*)d_ws;
        transpose_wv_kernel<<<dim3(12), dim3(256), 0, stream>>>(Wv, Wtv);
        att_head_ws<<<dim3(B_), dim3(1024), 0, stream>>>(x, Wk, Wq, Wtv, out);
    } else {
        att_head_kernel<<<dim3(B_), dim3(1024), 0, stream>>>(x, Wk, Wq, Wv, out);
    }
}

// Round 19
// 74.393 us; speedup vs baseline: 1.2561x; 1.2561x over previous
//
#include <hip/hip_runtime.h>
#include <hip/hip_bf16.h>

#define B_  512
#define T_  256
#define C_  384
#define H_  64
#define SCALE_ 0.05103103630798287f   // 384^-0.5

typedef float f32x4  __attribute__((ext_vector_type(4)));
typedef short bf16x8 __attribute__((ext_vector_type(8)));
typedef short bf16x4 __attribute__((ext_vector_type(4)));

__device__ __forceinline__ unsigned short f2bf(float f) {
    union { float f; unsigned u; } v; v.f = f;
    unsigned r = v.u + 0x7FFFu + ((v.u >> 16) & 1u);   // RNE
    return (unsigned short)(r >> 16);
}
__device__ __forceinline__ unsigned cvt_pk_bf16(float lo, float hi) {
    unsigned r;
    asm("v_cvt_pk_bf16_f32 %0, %1, %2" : "=v"(r) : "v"(lo), "v"(hi));
    return r;
}
// XOR-swizzled [R][64]-short tile index (row = 128 B = 8 x 16B blocks).
__device__ __forceinline__ int swz64(int row, int col) {
    return row * 64 + (((col >> 3) ^ (row & 7)) << 3) + (col & 7);
}

// LDS (shorts): smem[73728] = 147456 B.
//  Phase-1: wst[j] at j*12288, j=0..5 — all six W^T k=64 chunks resident
//  (R17-proven staging). ONE barrier, then phase 1 barrier-free.
//  Phase-2 (alias, after post-phase-1 barrier):
//    Ks[256][64] swz64   [0,     16384)
//    Qs[256][64] swz64   [16384, 32768)
//    Vt[64][264]         [32768, 49664)
//    Pb 16 x 2x[16][40]  [49664, 70144)
//
// Phase-1 wave grid (R7-proven): 8 row-bands (32 rows = 2 strips) x 2
// col-halves (96 cols = 6 frags) -> 12 B-frag b128 reads feed 24 MFMAs per
// chunk per wave (HALF of R17's per-CU B-read traffic). No x prefetch across
// chunks (register discipline; TLP + wave drift hide latency).
// Phase 2: R17-verbatim pipeline, qf sourced from block-shared Qs (R13 line).
__global__ __launch_bounds__(1024, 4) void att_head_kernel(
    const float* __restrict__ x,  const float* __restrict__ Wk,
    const float* __restrict__ Wq, const float* __restrict__ Wv,
    float* __restrict__ out)
{
    __shared__ __align__(16) short smem[73728];
    short* const Ks = smem;              // alias (live after phase 1)
    short* const Qs = smem + 16384;
    short* const Vt = smem + 32768;
    short* const Pb = smem + 49664;

    const int tid  = threadIdx.x;
    const int b    = blockIdx.x;
    const int w    = tid >> 6;        // 0..15
    const int lane = tid & 63;
    const int g    = lane >> 4;
    const int i    = lane & 15;
    const int wr   = w >> 1;          // row band: rows [32wr, 32wr+32)
    const int wc   = w & 1;           // col half: cols [96wc, 96wc+96)

    const float* xb = x + (size_t)b * T_ * C_;
    const float* Wm[3] = { Wk, Wq, Wv };

    f32x4 accP[2][6];
    #pragma unroll
    for (int m = 0; m < 2; m++)
        #pragma unroll
        for (int nb = 0; nb < 6; nb++) accP[m][nb] = f32x4{0.f, 0.f, 0.f, 0.f};

    // per-lane global bases for the wave's two A-strips
    const float* xs0 = xb + (size_t)(32 * wr + i) * C_ + g * 8;
    const float* xs1 = xs0 + 16 * C_;

    // ---- Stage ALL 6 W^T chunks (R17-verbatim, software-pipelined) ----
    {
        float wfa[12], wfb[12];
        auto loadWchunk = [&](int j, float* dst) {
            #pragma unroll
            for (int m = 0; m < 3; m++) {
                const float* Wp = Wm[m] + (size_t)(j * 64 + w * 4) * H_ + lane;
                #pragma unroll
                for (int jj = 0; jj < 4; jj++) dst[m * 4 + jj] = Wp[jj * H_];
            }
        };
        auto writeWchunk = [&](int j, const float* src) {
            short* buf = smem + j * 12288;
            #pragma unroll
            for (int m = 0; m < 3; m++) {
                union { unsigned u; short s[2]; } p0, p1;
                p0.u = cvt_pk_bf16(src[4 * m + 0], src[4 * m + 1]);
                p1.u = cvt_pk_bf16(src[4 * m + 2], src[4 * m + 3]);
                bf16x4 pk;
                pk[0] = p0.s[0]; pk[1] = p0.s[1]; pk[2] = p1.s[0]; pk[3] = p1.s[1];
                const int row = m * 64 + lane;
                const int k0  = w * 4;
                *(bf16x4*)&buf[row * 64 + (((k0 >> 3) ^ (row & 7)) << 3) + (k0 & 7)] = pk;
            }
        };
        loadWchunk(0, wfa);
        #pragma unroll
        for (int j = 0; j < 6; j++) {
            float* curW = (j & 1) ? wfb : wfa;
            float* nxtW = (j & 1) ? wfa : wfb;
            if (j < 5) loadWchunk(j + 1, nxtW);   // issue next loads first (T14)
            writeWchunk(j, curW);
        }
    }
    asm volatile("s_waitcnt lgkmcnt(0)\n\ts_barrier" ::: "memory");   // W^T resident

    // ---------------- Phase 1: 6 chunks of k=64, BARRIER-FREE, M=32 x N=96 -------
    #pragma unroll
    for (int j = 0; j < 6; j++) {
        const short* cur = smem + j * 12288;
        // load both strips' x (32 regs in flight), convert, free
        float4 xv[2][4];
        #pragma unroll
        for (int ks = 0; ks < 2; ks++) {
            xv[0][2 * ks]     = *(const float4*)(xs0 + 64 * j + 32 * ks);
            xv[0][2 * ks + 1] = *(const float4*)(xs0 + 64 * j + 32 * ks + 4);
            xv[1][2 * ks]     = *(const float4*)(xs1 + 64 * j + 32 * ks);
            xv[1][2 * ks + 1] = *(const float4*)(xs1 + 64 * j + 32 * ks + 4);
        }
        bf16x8 afs[2][2];
        #pragma unroll
        for (int m = 0; m < 2; m++)
            #pragma unroll
            for (int ks = 0; ks < 2; ks++) {
                union { bf16x8 v; unsigned u[4]; } a;
                a.u[0] = cvt_pk_bf16(xv[m][2 * ks].x,     xv[m][2 * ks].y);
                a.u[1] = cvt_pk_bf16(xv[m][2 * ks].z,     xv[m][2 * ks].w);
                a.u[2] = cvt_pk_bf16(xv[m][2 * ks + 1].x, xv[m][2 * ks + 1].y);
                a.u[3] = cvt_pk_bf16(xv[m][2 * ks + 1].z, xv[m][2 * ks + 1].w);
                afs[m][ks] = a.v;
            }
        // 12 B-reads feed 24 MFMAs
        #pragma unroll
        for (int nb = 0; nb < 6; nb++) {
            const int brow = 96 * wc + 16 * nb + i;
            #pragma unroll
            for (int ks = 0; ks < 2; ks++) {
                const bf16x8 bfr = *(const bf16x8*)&cur[brow * 64 +
                        (((ks * 4 + g) ^ (i & 7)) << 3)];
                accP[0][nb] = __builtin_amdgcn_mfma_f32_16x16x32_bf16(afs[0][ks], bfr, accP[0][nb], 0, 0, 0);
                accP[1][nb] = __builtin_amdgcn_mfma_f32_16x16x32_bf16(afs[1][ks], bfr, accP[1][nb], 0, 0, 0);
            }
        }
    }
    // all waves must finish reading wst before K/Q/V overwrite it
    asm volatile("s_waitcnt lgkmcnt(0)\n\ts_barrier" ::: "memory");

    // ---- Epilogue (R7-proven): scatter K,Q (b16, swz64) and V (packed b64) ----
    #pragma unroll
    for (int m = 0; m < 2; m++) {
        const int row0 = 32 * wr + 16 * m + 4 * g;
        #pragma unroll
        for (int nb = 0; nb < 6; nb++) {
            const int gc = 96 * wc + 16 * nb;   // wave-uniform
            if (gc < 64) {
                #pragma unroll
                for (int r = 0; r < 4; r++)
                    Ks[swz64(row0 + r, gc + i)] = (short)f2bf(accP[m][nb][r]);
            } else if (gc < 128) {
                #pragma unroll
                for (int r = 0; r < 4; r++)
                    Qs[swz64(row0 + r, gc - 64 + i)] = (short)f2bf(accP[m][nb][r]);
            } else {
                bf16x4 pk;
                #pragma unroll
                for (int r = 0; r < 4; r++) pk[r] = (short)f2bf(accP[m][nb][r]);
                *(bf16x4*)&Vt[(gc - 128 + i) * 264 + row0] = pk;
            }
        }
    }
    asm volatile("s_waitcnt lgkmcnt(0)\n\ts_barrier" ::: "memory");

    // ---------------- Phase 2 (R17 pipeline; qf from Qs, R13 line) ----------------
    const int rb = 16 * w;
    bf16x8 qf[2];
    #pragma unroll
    for (int ks = 0; ks < 2; ks++)
        qf[ks] = *(const bf16x8*)&Qs[(rb + i) * 64 + (((4 * ks + g) ^ (i & 7)) << 3)];

    short* const myP = Pb + w * 1280;    // two [16][40] buffers
    const float NEG_INF = -__builtin_inff();
    float mrun = NEG_INF, lrun = 0.f;
    f32x4 accO[4];
    #pragma unroll
    for (int ht = 0; ht < 4; ht++) accO[ht] = f32x4{0.f, 0.f, 0.f, 0.f};

    auto PVADD = [&](int bufsel, int ck) {
        const bf16x8 pf = *(const bf16x8*)&myP[bufsel * 640 + i * 40 + 8 * g];
        #pragma unroll
        for (int ht = 0; ht < 4; ht++) {
            const bf16x8 vf = *(const bf16x8*)&Vt[(16 * ht + i) * 264 + 32 * ck + 8 * g];
            accO[ht] = __builtin_amdgcn_mfma_f32_16x16x32_bf16(vf, pf, accO[ht], 0, 0, 0);
        }
    };

    const int npair = w >> 1;            // last pair index; pair p = tiles 2p, 2p+1
    #pragma unroll
    for (int p = 0; p < 8; p++) {
        if (p <= npair) {                // wave-uniform
            // QK^T (S^T tiles): lane holds (kv = 16*(2p+s)+4g+r, q = rb+i)
            f32x4 sA[2];
            sA[0] = f32x4{0.f, 0.f, 0.f, 0.f};
            sA[1] = f32x4{0.f, 0.f, 0.f, 0.f};
            #pragma unroll
            for (int s = 0; s < 2; s++) {
                const int nt = 2 * p + s;
                if (nt <= w) {           // wave-uniform
                    #pragma unroll
                    for (int ks = 0; ks < 2; ks++) {
                        const bf16x8 kfr = *(const bf16x8*)&Ks[(16 * nt + i) * 64 +
                                (((4 * ks + g) ^ (i & 7)) << 3)];
                        sA[s] = __builtin_amdgcn_mfma_f32_16x16x32_bf16(kfr, qf[ks], sA[s], 0, 0, 0);
                    }
                }
            }
            if (p > 0) PVADD((p - 1) & 1, p - 1);   // pipelined PV of prev pair

            float mt = NEG_INF;
            #pragma unroll
            for (int s = 0; s < 2; s++)
                #pragma unroll
                for (int r = 0; r < 4; r++) {
                    const int kv = 16 * (2 * p + s) + 4 * g + r;
                    const bool ok = (2 * p + s <= w) && (kv <= rb + i);
                    const float v = ok ? sA[s][r] * SCALE_ : NEG_INF;
                    sA[s][r] = v;
                    mt = fmaxf(mt, v);
                }
            mt = fmaxf(mt, __shfl_xor(mt, 16, 64));
            mt = fmaxf(mt, __shfl_xor(mt, 32, 64));

            if (!__all(mt <= mrun + 8.0f)) {        // defer-max (THR=8)
                const float mnew = fmaxf(mrun, mt);
                const float f = __expf(mrun - mnew);
                mrun = mnew; lrun *= f;
                #pragma unroll
                for (int ht = 0; ht < 4; ht++)
                    #pragma unroll
                    for (int r = 0; r < 4; r++) accO[ht][r] *= f;
            }
            #pragma unroll
            for (int s = 0; s < 2; s++) {
                const float p0 = __expf(sA[s][0] - mrun);
                const float p1 = __expf(sA[s][1] - mrun);
                const float p2 = __expf(sA[s][2] - mrun);
                const float p3 = __expf(sA[s][3] - mrun);
                lrun += (p0 + p1) + (p2 + p3);
                union { bf16x4 v; unsigned u[2]; } pk;
                pk.u[0] = cvt_pk_bf16(p0, p1);
                pk.u[1] = cvt_pk_bf16(p2, p3);
                *(bf16x4*)&myP[(p & 1) * 640 + i * 40 + 16 * s + 4 * g] = pk.v;
            }
        }
    }
    PVADD(npair & 1, npair);             // drain last pair

    // final denominator (sum across the 4 g-lanes of column q)
    lrun += __shfl_xor(lrun, 16, 64);
    lrun += __shfl_xor(lrun, 32, 64);
    const float inv = 1.f / lrun;

    // store O^T: lane holds (h = 16ht+4g+r, q = rb+i) -> float4 per ht
    float* orow = out + ((size_t)b * T_ + rb + i) * H_;
    #pragma unroll
    for (int ht = 0; ht < 4; ht++) {
        float4 o;
        o.x = accO[ht][0] * inv;
        o.y = accO[ht][1] * inv;
        o.z = accO[ht][2] * inv;
        o.w = accO[ht][3] * inv;
        *(float4*)&orow[16 * ht + 4 * g] = o;
    }
}

extern "C" void kernel_launch(void* const* d_in, const int* in_sizes, int n_in,
                              void* d_out, int out_size, void* d_ws, size_t ws_size,
                              hipStream_t stream) {
    const float* x  = (const float*)d_in[0];
    const float* Wk = (const float*)d_in[1];
    const float* Wq = (const float*)d_in[2];
    const float* Wv = (const float*)d_in[3];
    float* out = (float*)d_out;
    (void)d_ws; (void)ws_size; (void)in_sizes; (void)n_in; (void)out_size;
    att_head_kernel<<<dim3(B_), dim3(1024), 0, stream>>>(x, Wk, Wq, Wv, out);
}

// Round 20
// 56.525 us; speedup vs baseline: 1.6532x; 1.3161x over previous
//
#include <hip/hip_runtime.h>
#include <hip/hip_bf16.h>

#define B_  512
#define T_  256
#define C_  384
#define H_  64
#define SCALE_ 0.05103103630798287f   // 384^-0.5

typedef float f32x4  __attribute__((ext_vector_type(4)));
typedef short bf16x8 __attribute__((ext_vector_type(8)));
typedef short bf16x4 __attribute__((ext_vector_type(4)));

__device__ __forceinline__ unsigned short f2bf(float f) {
    union { float f; unsigned u; } v; v.f = f;
    unsigned r = v.u + 0x7FFFu + ((v.u >> 16) & 1u);   // RNE
    return (unsigned short)(r >> 16);
}
__device__ __forceinline__ unsigned cvt_pk_bf16(float lo, float hi) {
    unsigned r;
    asm("v_cvt_pk_bf16_f32 %0, %1, %2" : "=v"(r) : "v"(lo), "v"(hi));
    return r;
}
// XOR-swizzled [R][64]-short tile index (row = 128 B = 8 x 16B blocks).
__device__ __forceinline__ int swz64(int row, int col) {
    return row * 64 + (((col >> 3) ^ (row & 7)) << 3) + (col & 7);
}

// Wave -> q-strip permutation: 4x4 magic square (rows AND cols sum to 30).
// Whether HW assigns waves to SIMDs by w%4 or w/4, each SIMD's 4 strips sum
// to 30 (34 causal tile-units) -> phase-2 per-SIMD load perfectly balanced
// (natural mapping: worst SIMD ~54 units, 1.7x mean).
__constant__ int STRIP_MAP[16] = {0,14,13,3, 11,5,6,8, 7,9,10,4, 12,2,1,15};

// LDS (shorts): smem[73728] = 147456 B.  (R17-verbatim layout)
//  Phase-1: wst[j] at j*12288, j=0..5 — all six W^T k=64 chunks resident.
//  Phase-2 (alias): Ks[0,16384) swz64 | Vt[16384,33280) | Pb[33280,53760)
__global__ __launch_bounds__(1024, 4) void att_head_kernel(
    const float* __restrict__ x,  const float* __restrict__ Wk,
    const float* __restrict__ Wq, const float* __restrict__ Wv,
    float* __restrict__ out)
{
    __shared__ __align__(16) short smem[73728];
    short* const Ks = smem;              // alias (live after phase 1)
    short* const Vt = smem + 16384;
    short* const Pb = smem + 33280;

    const int tid  = threadIdx.x;
    const int b    = blockIdx.x;
    const int w    = tid >> 6;        // 0..15 (raw wave id: staging k-quad)
    const int lane = tid & 63;
    const int g    = lane >> 4;
    const int i    = lane & 15;
    const int sw   = STRIP_MAP[w];    // owned q-strip (phase 1 rows + phase 2)
    const int rb   = 16 * sw;

    const float* xb = x + (size_t)b * T_ * C_;
    const float* Wm[3] = { Wk, Wq, Wv };

    f32x4 accP[12];
    #pragma unroll
    for (int nb = 0; nb < 12; nb++) accP[nb] = f32x4{0.f, 0.f, 0.f, 0.f};

    // per-lane global base for this wave's A-rows
    const float* xrow = xb + (size_t)(rb + i) * C_ + g * 8;

    // ---- Stage ALL 6 W^T chunks (R17-verbatim; raw w = k-quad index) ----
    {
        float wfa[12], wfb[12];
        auto loadWchunk = [&](int j, float* dst) {
            #pragma unroll
            for (int m = 0; m < 3; m++) {
                const float* Wp = Wm[m] + (size_t)(j * 64 + w * 4) * H_ + lane;
                #pragma unroll
                for (int jj = 0; jj < 4; jj++) dst[m * 4 + jj] = Wp[jj * H_];
            }
        };
        auto writeWchunk = [&](int j, const float* src) {
            short* buf = smem + j * 12288;
            #pragma unroll
            for (int m = 0; m < 3; m++) {
                union { unsigned u; short s[2]; } p0, p1;
                p0.u = cvt_pk_bf16(src[4 * m + 0], src[4 * m + 1]);
                p1.u = cvt_pk_bf16(src[4 * m + 2], src[4 * m + 3]);
                bf16x4 pk;
                pk[0] = p0.s[0]; pk[1] = p0.s[1]; pk[2] = p1.s[0]; pk[3] = p1.s[1];
                const int row = m * 64 + lane;
                const int k0  = w * 4;
                *(bf16x4*)&buf[row * 64 + (((k0 >> 3) ^ (row & 7)) << 3) + (k0 & 7)] = pk;
            }
        };
        loadWchunk(0, wfa);
        #pragma unroll
        for (int j = 0; j < 6; j++) {
            float* curW = (j & 1) ? wfb : wfa;
            float* nxtW = (j & 1) ? wfa : wfb;
            if (j < 5) loadWchunk(j + 1, nxtW);   // issue next loads first (T14)
            writeWchunk(j, curW);
        }
    }
    // prefetch x chunk 0 (lands under the barrier wait)
    float4 xr[2][4];
    #pragma unroll
    for (int ks = 0; ks < 2; ks++)
        #pragma unroll
        for (int h = 0; h < 2; h++)
            xr[0][ks * 2 + h] = *(const float4*)(xrow + ks * 32 + h * 4);
    asm volatile("s_waitcnt lgkmcnt(0)\n\ts_barrier" ::: "memory");   // W^T resident

    // ---------------- Phase 1 (R17-verbatim): 6 chunks of k=64, barrier-free ------
    #pragma unroll
    for (int j = 0; j < 6; j++) {
        const int par = j & 1;
        const short* cur = smem + j * 12288;
        if (j < 5) {
            #pragma unroll
            for (int ks = 0; ks < 2; ks++)
                #pragma unroll
                for (int h = 0; h < 2; h++)
                    xr[par ^ 1][ks * 2 + h] = *(const float4*)(xrow + (j + 1) * 64 + ks * 32 + h * 4);
        }
        bf16x8 afs[2];
        #pragma unroll
        for (int ks = 0; ks < 2; ks++)
            #pragma unroll
            for (int h = 0; h < 2; h++) {
                const float4 v = xr[par][ks * 2 + h];
                afs[ks][h * 4 + 0] = (short)f2bf(v.x);
                afs[ks][h * 4 + 1] = (short)f2bf(v.y);
                afs[ks][h * 4 + 2] = (short)f2bf(v.z);
                afs[ks][h * 4 + 3] = (short)f2bf(v.w);
            }
        #pragma unroll
        for (int nb = 0; nb < 12; nb++) {
            #pragma unroll
            for (int ks = 0; ks < 2; ks++) {
                const int brow = nb * 16 + i;
                const bf16x8 bfr = *(const bf16x8*)&cur[brow * 64 + (((ks * 4 + g) ^ (i & 7)) << 3)];
                accP[nb] = __builtin_amdgcn_mfma_f32_16x16x32_bf16(afs[ks], bfr, accP[nb], 0, 0, 0);
            }
        }
    }
    // all waves must finish reading wst before K/Q/V overwrite it
    asm volatile("s_waitcnt lgkmcnt(0)\n\ts_barrier" ::: "memory");

    // ---------------- Epilogue (R17-verbatim, strip = sw) ----------------
    // (1) Q -> own Ks slice (rows rb..rb+16), wave-local transpose
    #pragma unroll
    for (int nb = 0; nb < 4; nb++)
        #pragma unroll
        for (int r = 0; r < 4; r++)
            Ks[swz64(rb + 4 * g + r, 16 * nb + i)] = (short)f2bf(accP[4 + nb][r]);
    asm volatile("s_waitcnt lgkmcnt(0)" ::: "memory");
    bf16x8 qf[2];
    #pragma unroll
    for (int ks = 0; ks < 2; ks++)
        qf[ks] = *(const bf16x8*)&Ks[(rb + i) * 64 + (((4 * ks + g) ^ (i & 7)) << 3)];
    asm volatile("s_waitcnt lgkmcnt(0)" ::: "memory");   // qf landed before overwrite
    // (2) K -> same slice (b16 scatter)
    #pragma unroll
    for (int nb = 0; nb < 4; nb++)
        #pragma unroll
        for (int r = 0; r < 4; r++)
            Ks[swz64(rb + 4 * g + r, 16 * nb + i)] = (short)f2bf(accP[nb][r]);
    // (3) V -> Vt[h][t], packed b64 (r-consecutive t)
    #pragma unroll
    for (int nb = 0; nb < 4; nb++) {
        bf16x4 pk;
        #pragma unroll
        for (int r = 0; r < 4; r++) pk[r] = (short)f2bf(accP[8 + nb][r]);
        *(bf16x4*)&Vt[(16 * nb + i) * 264 + rb + 4 * g] = pk;
    }
    asm volatile("s_waitcnt lgkmcnt(0)\n\ts_barrier" ::: "memory");

    // ---------------- Phase 2 (R17-verbatim, bounds on sw): online S^T ----------
    short* const myP = Pb + w * 1280;    // two [16][40] buffers (raw w: scratch slot)
    const float NEG_INF = -__builtin_inff();
    float mrun = NEG_INF, lrun = 0.f;
    f32x4 accO[4];
    #pragma unroll
    for (int ht = 0; ht < 4; ht++) accO[ht] = f32x4{0.f, 0.f, 0.f, 0.f};

    auto PVADD = [&](int bufsel, int ck) {
        const bf16x8 pf = *(const bf16x8*)&myP[bufsel * 640 + i * 40 + 8 * g];
        #pragma unroll
        for (int ht = 0; ht < 4; ht++) {
            const bf16x8 vf = *(const bf16x8*)&Vt[(16 * ht + i) * 264 + 32 * ck + 8 * g];
            accO[ht] = __builtin_amdgcn_mfma_f32_16x16x32_bf16(vf, pf, accO[ht], 0, 0, 0);
        }
    };

    const int npair = sw >> 1;           // last pair index; pair p = tiles 2p, 2p+1
    #pragma unroll
    for (int p = 0; p < 8; p++) {
        if (p <= npair) {                // wave-uniform
            // QK^T (S^T tiles): lane holds (kv = 16*(2p+s)+4g+r, q = rb+i)
            f32x4 sA[2];
            sA[0] = f32x4{0.f, 0.f, 0.f, 0.f};
            sA[1] = f32x4{0.f, 0.f, 0.f, 0.f};
            #pragma unroll
            for (int s = 0; s < 2; s++) {
                const int nt = 2 * p + s;
                if (nt <= sw) {          // wave-uniform
                    #pragma unroll
                    for (int ks = 0; ks < 2; ks++) {
                        const bf16x8 kfr = *(const bf16x8*)&Ks[(16 * nt + i) * 64 +
                                (((4 * ks + g) ^ (i & 7)) << 3)];
                        sA[s] = __builtin_amdgcn_mfma_f32_16x16x32_bf16(kfr, qf[ks], sA[s], 0, 0, 0);
                    }
                }
            }
            if (p > 0) PVADD((p - 1) & 1, p - 1);   // pipelined PV of prev pair

            float mt = NEG_INF;
            #pragma unroll
            for (int s = 0; s < 2; s++)
                #pragma unroll
                for (int r = 0; r < 4; r++) {
                    const int kv = 16 * (2 * p + s) + 4 * g + r;
                    const bool ok = (2 * p + s <= sw) && (kv <= rb + i);
                    const float v = ok ? sA[s][r] * SCALE_ : NEG_INF;
                    sA[s][r] = v;
                    mt = fmaxf(mt, v);
                }
            mt = fmaxf(mt, __shfl_xor(mt, 16, 64));
            mt = fmaxf(mt, __shfl_xor(mt, 32, 64));

            if (!__all(mt <= mrun + 8.0f)) {        // defer-max (THR=8)
                const float mnew = fmaxf(mrun, mt);
                const float f = __expf(mrun - mnew);
                mrun = mnew; lrun *= f;
                #pragma unroll
                for (int ht = 0; ht < 4; ht++)
                    #pragma unroll
                    for (int r = 0; r < 4; r++) accO[ht][r] *= f;
            }
            #pragma unroll
            for (int s = 0; s < 2; s++) {
                const float p0 = __expf(sA[s][0] - mrun);
                const float p1 = __expf(sA[s][1] - mrun);
                const float p2 = __expf(sA[s][2] - mrun);
                const float p3 = __expf(sA[s][3] - mrun);
                lrun += (p0 + p1) + (p2 + p3);
                union { bf16x4 v; unsigned u[2]; } pk;
                pk.u[0] = cvt_pk_bf16(p0, p1);
                pk.u[1] = cvt_pk_bf16(p2, p3);
                *(bf16x4*)&myP[(p & 1) * 640 + i * 40 + 16 * s + 4 * g] = pk.v;
            }
        }
    }
    PVADD(npair & 1, npair);             // drain last pair

    // final denominator (sum across the 4 g-lanes of column q)
    lrun += __shfl_xor(lrun, 16, 64);
    lrun += __shfl_xor(lrun, 32, 64);
    const float inv = 1.f / lrun;

    // store O^T: lane holds (h = 16ht+4g+r, q = rb+i) -> float4 per ht
    float* orow = out + ((size_t)b * T_ + rb + i) * H_;
    #pragma unroll
    for (int ht = 0; ht < 4; ht++) {
        float4 o;
        o.x = accO[ht][0] * inv;
        o.y = accO[ht][1] * inv;
        o.z = accO[ht][2] * inv;
        o.w = accO[ht][3] * inv;
        *(float4*)&orow[16 * ht + 4 * g] = o;
    }
}

extern "C" void kernel_launch(void* const* d_in, const int* in_sizes, int n_in,
                              void* d_out, int out_size, void* d_ws, size_t ws_size,
                              hipStream_t stream) {
    const float* x  = (const float*)d_in[0];
    const float* Wk = (const float*)d_in[1];
    const float* Wq = (const float*)d_in[2];
    const float* Wv = (const float*)d_in[3];
    float* out = (float*)d_out;
    (void)d_ws; (void)ws_size; (void)in_sizes; (void)n_in; (void)out_size;
    att_head_kernel<<<dim3(B_), dim3(1024), 0, stream>>>(x, Wk, Wq, Wv, out);
}